// Round 9
// baseline (187.804 us; speedup 1.0000x reference)
//
#include <hip/hip_runtime.h>
#include <hip/hip_bf16.h>

// B=32, S=2048, D=1024, C=256
//   top[b,s] = max_c sum_d (latent[c,d]*att_diag[d]) * (tm*embeds[b,s,d] + pos_table[rel+64,d])
//   p = softmax_s(top*m + (m-1)*NEG);  ctx[b,d] = tok_diag[d] * sum_s embeds*p
//
// Pass 1 (R4/R8 core): split-fp16 MFMA (hh + h*lo + lo*h), 256 thr / 4 waves
// / 128 tokens per block; wave owns 16 c-tiles x 2 token sets.
// R9 change: only W_hi staged via global_load_lds (16KB chunks, dbuf 32KB);
// W_lo fragments read per-wave from L2 into regs (wlo is 512KB, L2-resident)
// -> halves the per-kc LDS read burst (the modeled binder) + stage DMA.
// Flash epilogue (R8): block-local P[b,blk,d] = sum exp(l-M_b)*e, embeds
// L2-hot; k_finish computes global softmax stats + combines partials.
//
// ws: whi 512K | wlo 512K | top 256K | partial 2M | mblk 2K

#define HC 64
#define NEGV 1000000000000.0f

constexpr int Bb = 32, Ss = 2048, Dd = 1024, Cc = 256;
constexpr int NKC = 32;                 // k-chunks of 32
constexpr int CT = Cc / 16;             // 16 c-tiles
constexpr int NBLK = 16;                // 128-token blocks per batch

typedef _Float16 f16x8 __attribute__((ext_vector_type(8)));
typedef float    f32x4 __attribute__((ext_vector_type(4)));

// ---------------- Pass 0: W -> per-kc fragment chunks, fp16 hi/lo ----------
// layout: whi[kc][ct][lane][8] (16KB/kc), wlo same shape in separate buffer
// A-frag map: lane = (c%16) + 16*g holds A[c][k = kc*32 + 8g + i]
__global__ __launch_bounds__(256) void k_prep_w(
    const float* __restrict__ latent, const float* __restrict__ att_diag,
    _Float16* __restrict__ whi, _Float16* __restrict__ wlo)
{
    const int idx = blockIdx.x * 256 + threadIdx.x;   // c*Dd + k
    const int c = idx >> 10, k = idx & 1023;
    const float wv = latent[idx] * att_diag[k];
    const _Float16 h  = (_Float16)wv;
    const _Float16 lo = (_Float16)(wv - (float)h);
    const int kc = k >> 5, g = (k >> 3) & 3, i = k & 7;
    const int lane = (c & 15) + 16 * g, ct = c >> 4;
    const size_t base = (size_t)kc * 8192 + (size_t)ct * 512 + lane * 8 + i;
    whi[base] = h;
    wlo[base] = lo;
}

// ---------------- Pass 1: scores via MFMA, max, block-local ctx partial ----
__global__ __launch_bounds__(256, 2) void k_scores_mfma(
    const float* __restrict__ embeds,    // [B][S][D]
    const float* __restrict__ mask,      // [B][S]
    const float* __restrict__ pos_table, // [132][D]
    const float* __restrict__ tok_mult,  // [1]
    const int*   __restrict__ rel_ids,   // [B][S]
    const _Float16* __restrict__ whi,    // [NKC][CT][64][8]
    const _Float16* __restrict__ wlo,    // [NKC][CT][64][8]
    float* __restrict__ top,             // [B][S]
    float* __restrict__ partial,         // [B][NBLK][D]
    float* __restrict__ mblk)            // [B][NBLK]
{
    __shared__ _Float16 sbuf[2][8192];   // 2 x 16KB (hi only)
    __shared__ float l_sh[128];
    __shared__ float w_sh[128];
    __shared__ float red2[2];

    const int t  = threadIdx.x;
    const int wv = t >> 6;      // wave 0..3
    const int l  = t & 63;
    const int lr = l & 15;      // token within set / output col
    const int lg = l >> 4;      // k-group

    const int b     = blockIdx.x >> 4;   // 16 blocks of 128 tokens per batch
    const int blk16 = blockIdx.x & 15;
    const int s0    = blk16 * 128;

    const float tm = tok_mult[0];

    const float* erow[2];
    const float* prow[2];
    #pragma unroll
    for (int st = 0; st < 2; st++) {
        const int tok = s0 + wv * 32 + st * 16 + lr;
        erow[st] = embeds + ((size_t)b * Ss + tok) * Dd;
        prow[st] = pos_table + (size_t)(rel_ids[b * Ss + tok] + HC) * Dd;
    }

    f32x4 acc[CT][2];
    #pragma unroll
    for (int ct = 0; ct < CT; ct++)
        #pragma unroll
        for (int st = 0; st < 2; st++) acc[ct][st] = (f32x4){0.f, 0.f, 0.f, 0.f};

    // raw e/p prefetch registers (one kc ahead)
    f32x4 e0[2], e1[2], p0[2], p1[2];
    auto loadEP = [&](int kc) {
        const int k0 = kc * 32 + lg * 8;
        #pragma unroll
        for (int st = 0; st < 2; st++) {
            e0[st] = *(const f32x4*)(erow[st] + k0);
            e1[st] = *(const f32x4*)(erow[st] + k0 + 4);
            p0[st] = *(const f32x4*)(prow[st] + k0);
            p1[st] = *(const f32x4*)(prow[st] + k0 + 4);
        }
    };

    // stage one 16KB W_hi chunk: 16 wave-chunks of 1KB (4 per wave)
    auto stage = [&](int kc, _Float16* dst) {
        const _Float16* src = whi + (size_t)kc * 8192;
        #pragma unroll
        for (int i = 0; i < 4; i++) {
            const int off = (i * 4 + wv) << 9;   // elems; 1KB chunks
            __builtin_amdgcn_global_load_lds(
                (const __attribute__((address_space(1))) void*)(src + off + l * 8),
                (__attribute__((address_space(3))) void*)(dst + off),
                16, 0, 0);
        }
    };

    const f16x8* wlo8 = (const f16x8*)wlo;   // [kc*1024 + ct*64 + l]

    loadEP(0);
    stage(0, sbuf[0]);
    __syncthreads();   // drains vmcnt: stage(0) + loadEP(0) complete

    int cur = 0;
    for (int kc = 0; kc < NKC; kc++) {
        if (kc + 1 < NKC) stage(kc + 1, sbuf[cur ^ 1]);

        // build current B frags (hi/lo fp16) from prefetched raws
        f16x8 bh[2], bl[2];
        #pragma unroll
        for (int st = 0; st < 2; st++) {
            float e[8], p[8];
            *(f32x4*)&e[0] = e0[st]; *(f32x4*)&e[4] = e1[st];
            *(f32x4*)&p[0] = p0[st]; *(f32x4*)&p[4] = p1[st];
            #pragma unroll
            for (int i = 0; i < 8; i++) {
                const float x = fmaf(tm, e[i], p[i]);
                const _Float16 h = (_Float16)x;
                bh[st][i] = h;
                bl[st][i] = (_Float16)(x - (float)h);
            }
        }
        if (kc + 1 < NKC) loadEP(kc + 1);   // issue next-kc e/p early

        const _Float16* base = sbuf[cur];
        const int lobase = kc * 1024 + l;
        #pragma unroll
        for (int ct = 0; ct < CT; ct++) {
            const f16x8 al = wlo8[lobase + ct * 64];          // L2 -> reg
            const f16x8 ah = *(const f16x8*)(base + ct * 512 + l * 8);
            #pragma unroll
            for (int st = 0; st < 2; st++) {
                acc[ct][st] = __builtin_amdgcn_mfma_f32_16x16x32_f16(ah, bh[st], acc[ct][st], 0, 0, 0);
                acc[ct][st] = __builtin_amdgcn_mfma_f32_16x16x32_f16(ah, bl[st], acc[ct][st], 0, 0, 0);
                acc[ct][st] = __builtin_amdgcn_mfma_f32_16x16x32_f16(al, bh[st], acc[ct][st], 0, 0, 0);
            }
        }
        __syncthreads();   // stage(kc+1) done; all waves done reading sbuf[cur]
        cur ^= 1;
    }

    // masked logit per token; stash in LDS for the flash epilogue
    #pragma unroll
    for (int st = 0; st < 2; st++) {
        float mx = acc[0][st][0];
        #pragma unroll
        for (int ct = 0; ct < CT; ct++)
            #pragma unroll
            for (int r = 0; r < 4; r++) mx = fmaxf(mx, acc[ct][st][r]);
        mx = fmaxf(mx, __shfl_xor(mx, 16));
        mx = fmaxf(mx, __shfl_xor(mx, 32));
        if (lg == 0) {
            const int si = wv * 32 + st * 16 + lr;   // token within block
            const int s  = s0 + si;
            const float mk = mask[b * Ss + s];
            const float lv = mx * mk + (mk - 1.0f) * NEGV;
            top[b * Ss + s] = lv;
            l_sh[si] = lv;
        }
    }
    __syncthreads();

    // block max M_b over the 128 logits
    if (t < 128) {
        float v = l_sh[t];
        #pragma unroll
        for (int o = 32; o >= 1; o >>= 1) v = fmaxf(v, __shfl_xor(v, o));
        if ((t & 63) == 0) red2[t >> 6] = v;
    }
    __syncthreads();
    const float Mb = fmaxf(red2[0], red2[1]);
    if (t < 128) w_sh[t] = expf(l_sh[t] - Mb);
    __syncthreads();

    // block-local ctx partial: P[d] = sum_s w_sh[s] * e[s0+s][d]  (L2-hot)
    {
        const float* eb = embeds + ((size_t)b * Ss + s0) * Dd + t * 4;
        f32x4 ca = (f32x4){0.f, 0.f, 0.f, 0.f};
        #pragma unroll 8
        for (int s = 0; s < 128; s++) {
            const float wgt = w_sh[s];
            const f32x4 ev = *(const f32x4*)(eb + (size_t)s * Dd);
            ca[0] = fmaf(wgt, ev[0], ca[0]);
            ca[1] = fmaf(wgt, ev[1], ca[1]);
            ca[2] = fmaf(wgt, ev[2], ca[2]);
            ca[3] = fmaf(wgt, ev[3], ca[3]);
        }
        *(f32x4*)(partial + ((size_t)(b * NBLK + blk16)) * Dd + t * 4) = ca;
        if (t == 0) mblk[b * NBLK + blk16] = Mb;
    }
}

// ------- Pass 2: global softmax stats + combine partials + tok_diag -------
__global__ __launch_bounds__(256) void k_finish(
    const float* __restrict__ top, const float* __restrict__ mblk,
    const float* __restrict__ partial, const float* __restrict__ tok_diag,
    float* __restrict__ out)
{
    const int b = blockIdx.x, t = threadIdx.x;
    const float* row = top + (size_t)b * Ss;
    float v[8];
    #pragma unroll
    for (int i = 0; i < 8; i++) v[i] = row[t + 256 * i];

    float mx = v[0];
    #pragma unroll
    for (int i = 1; i < 8; i++) mx = fmaxf(mx, v[i]);
    #pragma unroll
    for (int o = 32; o >= 1; o >>= 1) mx = fmaxf(mx, __shfl_xor(mx, o));

    __shared__ float redm[4], reds[4];
    __shared__ float cf[NBLK];
    const int w = t >> 6, ln = t & 63;
    if (ln == 0) redm[w] = mx;
    __syncthreads();
    mx = fmaxf(fmaxf(redm[0], redm[1]), fmaxf(redm[2], redm[3]));

    float sum = 0.f;
    #pragma unroll
    for (int i = 0; i < 8; i++) sum += expf(v[i] - mx);
    #pragma unroll
    for (int o = 32; o >= 1; o >>= 1) sum += __shfl_xor(sum, o);
    if (ln == 0) reds[w] = sum;
    __syncthreads();
    sum = reds[0] + reds[1] + reds[2] + reds[3];

    if (t < NBLK) cf[t] = expf(mblk[b * NBLK + t] - mx) / sum;
    __syncthreads();

    const int d = t * 4;
    f32x4 a = (f32x4){0.f, 0.f, 0.f, 0.f};
    #pragma unroll
    for (int j = 0; j < NBLK; j++) {
        const float c = cf[j];
        const f32x4 p = *(const f32x4*)(partial + ((size_t)(b * NBLK + j)) * Dd + d);
        a[0] = fmaf(c, p[0], a[0]);
        a[1] = fmaf(c, p[1], a[1]);
        a[2] = fmaf(c, p[2], a[2]);
        a[3] = fmaf(c, p[3], a[3]);
    }
    const f32x4 td = *(const f32x4*)(tok_diag + d);
    f32x4 o = a * td;
    *(f32x4*)(out + (size_t)b * Dd + d) = o;
}

extern "C" void kernel_launch(void* const* d_in, const int* in_sizes, int n_in,
                              void* d_out, int out_size, void* d_ws, size_t ws_size,
                              hipStream_t stream) {
    const float* embeds    = (const float*)d_in[0];
    const float* mask      = (const float*)d_in[1];
    const float* latent    = (const float*)d_in[2];
    const float* att_diag  = (const float*)d_in[3];
    const float* tok_diag  = (const float*)d_in[4];
    const float* pos_table = (const float*)d_in[5];
    const float* tok_mult  = (const float*)d_in[6];
    const int*   rel_ids   = (const int*)d_in[7];
    float* out = (float*)d_out;

    char* ws = (char*)d_ws;
    _Float16* whi    = (_Float16*)(ws);              // 512 KB
    _Float16* wlo    = (_Float16*)(ws + 524288);     // 512 KB
    float*    top    = (float*)(ws + 1048576);       // 256 KB
    float*    partial= (float*)(ws + 1310720);       // 2 MB
    float*    mblk   = (float*)(ws + 3407872);       // 2 KB

    k_prep_w<<<(Cc * Dd) / 256, 256, 0, stream>>>(latent, att_diag, whi, wlo);
    k_scores_mfma<<<(Bb * Ss) / 128, 256, 0, stream>>>(
        embeds, mask, pos_table, tok_mult, rel_ids, whi, wlo, top, partial, mblk);
    k_finish<<<Bb, 256, 0, stream>>>(top, mblk, partial, tok_diag, out);
}

// Round 10
// 126.325 us; speedup vs baseline: 1.4867x; 1.4867x over previous
//
#include <hip/hip_runtime.h>
#include <hip/hip_bf16.h>

// B=32, S=2048, D=1024, C=256
//   top[b,s] = max_c sum_d (latent[c,d]*att_diag[d]) * (tm*embeds[b,s,d] + pos_table[rel+64,d])
//   p = softmax_s(top*m + (m-1)*NEG);  ctx[b,d] = tok_diag[d] * sum_s embeds*p
//
// R10: 2-term split-fp16 MFMA:  W_hi * (e_hi + e_lo)   (W rounded to fp16;
// err ~ sum w_lo*e ~ 0.02 on sigma=45 logits -> well under threshold).
// Only W_hi staged via global_load_lds (16KB/kc, dbuf 32KB). Blocks of 64
// tokens / 2 waves / grid 1024 -> 4 independent blocks per CU (4 barrier
// domains overlap each other's stage drains). Wave owns 16 c-tiles x 2
// token-sets (acc=128). Flash epilogue per block: M_b, Z_b, P[b,blk,d];
// k_finish combines (no top buffer, no probs).
//
// ws: whi 512K | partial 4M | mblk 4K | zblk 4K

#define HC 64
#define NEGV 1000000000000.0f

constexpr int Bb = 32, Ss = 2048, Dd = 1024, Cc = 256;
constexpr int NKC = 32;                 // k-chunks of 32
constexpr int CT = Cc / 16;             // 16 c-tiles
constexpr int NBLK = 32;                // 64-token blocks per batch

typedef _Float16 f16x8 __attribute__((ext_vector_type(8)));
typedef float    f32x4 __attribute__((ext_vector_type(4)));

// ---------------- Pass 0: W_hi -> per-kc fragment chunks ----------
// layout: whi[kc][ct][lane][8] (16KB/kc)
// A-frag map: lane = (c%16) + 16*g holds A[c][k = kc*32 + 8g + i]
__global__ __launch_bounds__(256) void k_prep_w(
    const float* __restrict__ latent, const float* __restrict__ att_diag,
    _Float16* __restrict__ whi)
{
    const int idx = blockIdx.x * 256 + threadIdx.x;   // c*Dd + k
    const int c = idx >> 10, k = idx & 1023;
    const float wv = latent[idx] * att_diag[k];
    const int kc = k >> 5, g = (k >> 3) & 3, i = k & 7;
    const int lane = (c & 15) + 16 * g, ct = c >> 4;
    whi[(size_t)kc * 8192 + (size_t)ct * 512 + lane * 8 + i] = (_Float16)wv;
}

// ------- Pass 1: scores via MFMA, block max/sumexp, flash ctx partial -----
__global__ __launch_bounds__(128, 2) void k_scores_mfma(
    const float* __restrict__ embeds,    // [B][S][D]
    const float* __restrict__ mask,      // [B][S]
    const float* __restrict__ pos_table, // [132][D]
    const float* __restrict__ tok_mult,  // [1]
    const int*   __restrict__ rel_ids,   // [B][S]
    const _Float16* __restrict__ whi,    // [NKC][CT][64][8]
    float* __restrict__ partial,         // [B][NBLK][D]
    float* __restrict__ mblk,            // [B][NBLK]
    float* __restrict__ zblk)            // [B][NBLK]
{
    __shared__ _Float16 sbuf[2][8192];   // 2 x 16KB (W_hi chunks)
    __shared__ float l_sh[64];
    __shared__ float w_sh[64];
    __shared__ float red1[2];

    const int t  = threadIdx.x;
    const int wv = t >> 6;      // wave 0..1
    const int l  = t & 63;
    const int lr = l & 15;      // token within set / output col
    const int lg = l >> 4;      // k-group

    const int b   = blockIdx.x >> 5;     // 32 blocks of 64 tokens per batch
    const int blk = blockIdx.x & 31;
    const int s0  = blk * 64;

    const float tm = tok_mult[0];

    const float* erow[2];
    const float* prow[2];
    #pragma unroll
    for (int st = 0; st < 2; st++) {
        const int tok = s0 + wv * 32 + st * 16 + lr;
        erow[st] = embeds + ((size_t)b * Ss + tok) * Dd;
        prow[st] = pos_table + (size_t)(rel_ids[b * Ss + tok] + HC) * Dd;
    }

    f32x4 acc[CT][2];
    #pragma unroll
    for (int ct = 0; ct < CT; ct++)
        #pragma unroll
        for (int st = 0; st < 2; st++) acc[ct][st] = (f32x4){0.f, 0.f, 0.f, 0.f};

    // raw e/p prefetch registers (one kc ahead)
    f32x4 e0[2], e1[2], p0[2], p1[2];
    auto loadEP = [&](int kc) {
        const int k0 = kc * 32 + lg * 8;
        #pragma unroll
        for (int st = 0; st < 2; st++) {
            e0[st] = *(const f32x4*)(erow[st] + k0);
            e1[st] = *(const f32x4*)(erow[st] + k0 + 4);
            p0[st] = *(const f32x4*)(prow[st] + k0);
            p1[st] = *(const f32x4*)(prow[st] + k0 + 4);
        }
    };

    // stage one 16KB W_hi chunk: 16 wave-chunks of 1KB (8 per wave)
    auto stage = [&](int kc, _Float16* dst) {
        const _Float16* src = whi + (size_t)kc * 8192;
        #pragma unroll
        for (int i = 0; i < 8; i++) {
            const int off = (i * 2 + wv) << 9;   // elems; 1KB chunks
            __builtin_amdgcn_global_load_lds(
                (const __attribute__((address_space(1))) void*)(src + off + l * 8),
                (__attribute__((address_space(3))) void*)(dst + off),
                16, 0, 0);
        }
    };

    loadEP(0);
    stage(0, sbuf[0]);
    __syncthreads();   // drains vmcnt: stage(0) + loadEP(0) complete

    int cur = 0;
    for (int kc = 0; kc < NKC; kc++) {
        if (kc + 1 < NKC) stage(kc + 1, sbuf[cur ^ 1]);

        // build current B frags (e split hi/lo fp16) from prefetched raws
        f16x8 bh[2], bl[2];
        #pragma unroll
        for (int st = 0; st < 2; st++) {
            float e[8], p[8];
            *(f32x4*)&e[0] = e0[st]; *(f32x4*)&e[4] = e1[st];
            *(f32x4*)&p[0] = p0[st]; *(f32x4*)&p[4] = p1[st];
            #pragma unroll
            for (int i = 0; i < 8; i++) {
                const float x = fmaf(tm, e[i], p[i]);
                const _Float16 h = (_Float16)x;
                bh[st][i] = h;
                bl[st][i] = (_Float16)(x - (float)h);
            }
        }
        if (kc + 1 < NKC) loadEP(kc + 1);   // issue next-kc e/p early

        const _Float16* base = sbuf[cur];
        #pragma unroll
        for (int ct = 0; ct < CT; ct++) {
            const f16x8 ah = *(const f16x8*)(base + ct * 512 + l * 8);
            #pragma unroll
            for (int st = 0; st < 2; st++) {
                acc[ct][st] = __builtin_amdgcn_mfma_f32_16x16x32_f16(ah, bh[st], acc[ct][st], 0, 0, 0);
                acc[ct][st] = __builtin_amdgcn_mfma_f32_16x16x32_f16(ah, bl[st], acc[ct][st], 0, 0, 0);
            }
        }
        __syncthreads();   // stage(kc+1) done; all waves done reading sbuf[cur]
        cur ^= 1;
    }

    // masked logit per token -> LDS
    #pragma unroll
    for (int st = 0; st < 2; st++) {
        float mx = acc[0][st][0];
        #pragma unroll
        for (int ct = 0; ct < CT; ct++)
            #pragma unroll
            for (int r = 0; r < 4; r++) mx = fmaxf(mx, acc[ct][st][r]);
        mx = fmaxf(mx, __shfl_xor(mx, 16));
        mx = fmaxf(mx, __shfl_xor(mx, 32));
        if (lg == 0) {
            const int si = wv * 32 + st * 16 + lr;   // token within block
            const int s  = s0 + si;
            const float mk = mask[b * Ss + s];
            l_sh[si] = mx * mk + (mk - 1.0f) * NEGV;
        }
    }
    __syncthreads();

    // block max M_b over 64 logits (wave 0 does the reduce)
    if (t < 64) {
        float v = l_sh[t];
        #pragma unroll
        for (int o = 32; o >= 1; o >>= 1) v = fmaxf(v, __shfl_xor(v, o));
        if (t == 0) red1[0] = v;
    }
    __syncthreads();
    const float Mb = red1[0];
    if (t < 64) w_sh[t] = expf(l_sh[t] - Mb);
    __syncthreads();
    if (t < 64) {
        float z = w_sh[t];
        #pragma unroll
        for (int o = 32; o >= 1; o >>= 1) z += __shfl_xor(z, o);
        if (t == 0) { red1[1] = z; }
    }

    // block-local ctx partial: P[d] = sum_s w_sh[s] * e[s0+s][d]  (L2-hot)
    {
        const float* eb = embeds + ((size_t)b * Ss + s0) * Dd + t * 8;
        f32x4 ca = (f32x4){0.f, 0.f, 0.f, 0.f};
        f32x4 cb = (f32x4){0.f, 0.f, 0.f, 0.f};
        #pragma unroll 4
        for (int s = 0; s < 64; s++) {
            const float wgt = w_sh[s];
            const f32x4 ev = *(const f32x4*)(eb + (size_t)s * Dd);
            const f32x4 ew = *(const f32x4*)(eb + (size_t)s * Dd + 4);
            ca[0] = fmaf(wgt, ev[0], ca[0]);
            ca[1] = fmaf(wgt, ev[1], ca[1]);
            ca[2] = fmaf(wgt, ev[2], ca[2]);
            ca[3] = fmaf(wgt, ev[3], ca[3]);
            cb[0] = fmaf(wgt, ew[0], cb[0]);
            cb[1] = fmaf(wgt, ew[1], cb[1]);
            cb[2] = fmaf(wgt, ew[2], cb[2]);
            cb[3] = fmaf(wgt, ew[3], cb[3]);
        }
        float* pdst = partial + ((size_t)(b * NBLK + blk)) * Dd + t * 8;
        *(f32x4*)(pdst)     = ca;
        *(f32x4*)(pdst + 4) = cb;
        if (t == 0) {
            mblk[b * NBLK + blk] = Mb;
            zblk[b * NBLK + blk] = red1[1];
        }
    }
}

// ------- Pass 2: global flash combine + tok_diag -------
__global__ __launch_bounds__(256) void k_finish(
    const float* __restrict__ mblk, const float* __restrict__ zblk,
    const float* __restrict__ partial, const float* __restrict__ tok_diag,
    float* __restrict__ out)
{
    __shared__ float cf[NBLK];
    const int b = blockIdx.x, t = threadIdx.x;

    if (t < 64) {
        // lane j<NBLK computes via wave-wide reduce over 64 lanes (pad with NEG)
        const float mv = (t < NBLK) ? mblk[b * NBLK + t] : -3.4e38f;
        float M = mv;
        #pragma unroll
        for (int o = 32; o >= 1; o >>= 1) M = fmaxf(M, __shfl_xor(M, o));
        const float zv = (t < NBLK) ? zblk[b * NBLK + t] * expf(mv - M) : 0.f;
        float Z = zv;
        #pragma unroll
        for (int o = 32; o >= 1; o >>= 1) Z += __shfl_xor(Z, o);
        if (t < NBLK) cf[t] = expf(mv - M) / Z;
    }
    __syncthreads();

    const int d = t * 4;
    f32x4 a = (f32x4){0.f, 0.f, 0.f, 0.f};
    #pragma unroll
    for (int j = 0; j < NBLK; j++) {
        const float c = cf[j];
        const f32x4 p = *(const f32x4*)(partial + ((size_t)(b * NBLK + j)) * Dd + d);
        a[0] = fmaf(c, p[0], a[0]);
        a[1] = fmaf(c, p[1], a[1]);
        a[2] = fmaf(c, p[2], a[2]);
        a[3] = fmaf(c, p[3], a[3]);
    }
    const f32x4 td = *(const f32x4*)(tok_diag + d);
    f32x4 o = a * td;
    *(f32x4*)(out + (size_t)b * Dd + d) = o;
}

extern "C" void kernel_launch(void* const* d_in, const int* in_sizes, int n_in,
                              void* d_out, int out_size, void* d_ws, size_t ws_size,
                              hipStream_t stream) {
    const float* embeds    = (const float*)d_in[0];
    const float* mask      = (const float*)d_in[1];
    const float* latent    = (const float*)d_in[2];
    const float* att_diag  = (const float*)d_in[3];
    const float* tok_diag  = (const float*)d_in[4];
    const float* pos_table = (const float*)d_in[5];
    const float* tok_mult  = (const float*)d_in[6];
    const int*   rel_ids   = (const int*)d_in[7];
    float* out = (float*)d_out;

    char* ws = (char*)d_ws;
    _Float16* whi    = (_Float16*)(ws);              // 512 KB
    float*    partial= (float*)(ws + 524288);        // 4 MB
    float*    mblk   = (float*)(ws + 4718592);       // 4 KB
    float*    zblk   = (float*)(ws + 4722688);       // 4 KB

    k_prep_w<<<(Cc * Dd) / 256, 256, 0, stream>>>(latent, att_diag, whi);
    k_scores_mfma<<<Bb * NBLK, 128, 0, stream>>>(
        embeds, mask, pos_table, tok_mult, rel_ids, whi, partial, mblk, zblk);
    k_finish<<<Bb, 256, 0, stream>>>(mblk, zblk, partial, tok_diag, out);
}

// Round 11
// 121.926 us; speedup vs baseline: 1.5403x; 1.0361x over previous
//
#include <hip/hip_runtime.h>
#include <hip/hip_bf16.h>

// B=32, S=2048, D=1024, C=256
//   top[b,s] = max_c sum_d (latent[c,d]*att_diag[d]) * (tm*embeds[b,s,d] + pos_table[rel+64,d])
//   p = softmax_s(top*m + (m-1)*NEG);  ctx[b,d] = tok_diag[d] * sum_s embeds*p
//
// R11: R8 skeleton (4 waves / 128 tokens / dbuf LDS W staging) with:
//  - 2-term split-fp16 MFMA: W_hi * (e_hi + e_lo)   (absmax ~0.06 < 0.21)
//  - counted-vmcnt barrier: s_waitcnt vmcnt(8) + raw s_barrier per kc, so the
//    8 e/p HBM prefetch loads stay in flight across the barrier (only the 4
//    L2 stage loads must land). Kills the per-kc vmcnt(0) drain stall.
//  - flash epilogue with per-block (M_b, Z_b); k_finish combines partials.
//
// ws: whi 512K | partial 2M | mblk 2K | zblk 2K

#define HC 64
#define NEGV 1000000000000.0f

constexpr int Bb = 32, Ss = 2048, Dd = 1024, Cc = 256;
constexpr int NKC = 32;                 // k-chunks of 32
constexpr int CT = Cc / 16;             // 16 c-tiles
constexpr int NBLK = 16;                // 128-token blocks per batch

typedef _Float16 f16x8 __attribute__((ext_vector_type(8)));
typedef float    f32x4 __attribute__((ext_vector_type(4)));

// ---------------- Pass 0: W_hi -> per-kc fragment chunks ----------
// layout: whi[kc][ct][lane][8] (16KB/kc)
// A-frag map: lane = (c%16) + 16*g holds A[c][k = kc*32 + 8g + i]
__global__ __launch_bounds__(256) void k_prep_w(
    const float* __restrict__ latent, const float* __restrict__ att_diag,
    _Float16* __restrict__ whi)
{
    const int idx = blockIdx.x * 256 + threadIdx.x;   // c*Dd + k
    const int c = idx >> 10, k = idx & 1023;
    const float wv = latent[idx] * att_diag[k];
    const int kc = k >> 5, g = (k >> 3) & 3, i = k & 7;
    const int lane = (c & 15) + 16 * g, ct = c >> 4;
    whi[(size_t)kc * 8192 + (size_t)ct * 512 + lane * 8 + i] = (_Float16)wv;
}

// ------- Pass 1: scores via MFMA, block max/sumexp, flash ctx partial -----
__global__ __launch_bounds__(256, 2) void k_scores_mfma(
    const float* __restrict__ embeds,    // [B][S][D]
    const float* __restrict__ mask,      // [B][S]
    const float* __restrict__ pos_table, // [132][D]
    const float* __restrict__ tok_mult,  // [1]
    const int*   __restrict__ rel_ids,   // [B][S]
    const _Float16* __restrict__ whi,    // [NKC][CT][64][8]
    float* __restrict__ partial,         // [B][NBLK][D]
    float* __restrict__ mblk,            // [B][NBLK]
    float* __restrict__ zblk)            // [B][NBLK]
{
    __shared__ _Float16 sbuf[2][8192];   // 2 x 16KB (W_hi chunks)
    __shared__ float l_sh[128];
    __shared__ float w_sh[128];
    __shared__ float red2[2];
    __shared__ float zred[2];

    const int t  = threadIdx.x;
    const int wv = t >> 6;      // wave 0..3
    const int l  = t & 63;
    const int lr = l & 15;      // token within set / output col
    const int lg = l >> 4;      // k-group

    const int b   = blockIdx.x >> 4;     // 16 blocks of 128 tokens per batch
    const int blk = blockIdx.x & 15;
    const int s0  = blk * 128;

    const float tm = tok_mult[0];

    const float* erow[2];
    const float* prow[2];
    #pragma unroll
    for (int st = 0; st < 2; st++) {
        const int tok = s0 + wv * 32 + st * 16 + lr;
        erow[st] = embeds + ((size_t)b * Ss + tok) * Dd;
        prow[st] = pos_table + (size_t)(rel_ids[b * Ss + tok] + HC) * Dd;
    }

    f32x4 acc[CT][2];
    #pragma unroll
    for (int ct = 0; ct < CT; ct++)
        #pragma unroll
        for (int st = 0; st < 2; st++) acc[ct][st] = (f32x4){0.f, 0.f, 0.f, 0.f};

    // raw e/p prefetch registers (one kc ahead): 8 global loads per call
    f32x4 e0[2], e1[2], p0[2], p1[2];
    auto loadEP = [&](int kc) {
        const int k0 = kc * 32 + lg * 8;
        #pragma unroll
        for (int st = 0; st < 2; st++) {
            e0[st] = *(const f32x4*)(erow[st] + k0);
            e1[st] = *(const f32x4*)(erow[st] + k0 + 4);
            p0[st] = *(const f32x4*)(prow[st] + k0);
            p1[st] = *(const f32x4*)(prow[st] + k0 + 4);
        }
    };

    // stage one 16KB W_hi chunk: 16 wave-chunks of 1KB (4 per wave)
    auto stage = [&](int kc, _Float16* dst) {
        const _Float16* src = whi + (size_t)kc * 8192;
        #pragma unroll
        for (int i = 0; i < 4; i++) {
            const int off = (i * 4 + wv) << 9;   // elems; 1KB chunks
            __builtin_amdgcn_global_load_lds(
                (const __attribute__((address_space(1))) void*)(src + off + l * 8),
                (__attribute__((address_space(3))) void*)(dst + off),
                16, 0, 0);
        }
    };

    // prologue: stage first (oldest), then e/p
    stage(0, sbuf[0]);
    loadEP(0);
    asm volatile("s_waitcnt vmcnt(8)" ::: "memory");  // stage(0) done (e/p may fly)
    __builtin_amdgcn_s_barrier();

    int cur = 0;
    for (int kc = 0; kc < NKC; kc++) {
        if (kc + 1 < NKC) stage(kc + 1, sbuf[cur ^ 1]);   // oldest VMEM this iter

        // build current B frags (e split hi/lo fp16); consumes e/p(kc) regs
        f16x8 bh[2], bl[2];
        #pragma unroll
        for (int st = 0; st < 2; st++) {
            float e[8], p[8];
            *(f32x4*)&e[0] = e0[st]; *(f32x4*)&e[4] = e1[st];
            *(f32x4*)&p[0] = p0[st]; *(f32x4*)&p[4] = p1[st];
            #pragma unroll
            for (int i = 0; i < 8; i++) {
                const float x = fmaf(tm, e[i], p[i]);
                const _Float16 h = (_Float16)x;
                bh[st][i] = h;
                bl[st][i] = (_Float16)(x - (float)h);
            }
        }
        if (kc + 1 < NKC) loadEP(kc + 1);   // 8 HBM loads; stay in flight past barrier

        const _Float16* base = sbuf[cur];
        #pragma unroll
        for (int ct = 0; ct < CT; ct++) {
            const f16x8 ah = *(const f16x8*)(base + ct * 512 + l * 8);
            #pragma unroll
            for (int st = 0; st < 2; st++) {
                acc[ct][st] = __builtin_amdgcn_mfma_f32_16x16x32_f16(ah, bh[st], acc[ct][st], 0, 0, 0);
                acc[ct][st] = __builtin_amdgcn_mfma_f32_16x16x32_f16(ah, bl[st], acc[ct][st], 0, 0, 0);
            }
        }
        // wait only for this iter's 4 stage loads (oldest); e/p(kc+1) stays in flight
        asm volatile("s_waitcnt vmcnt(8)" ::: "memory");
        __builtin_amdgcn_s_barrier();
        cur ^= 1;
    }

    // masked logit per token -> LDS
    #pragma unroll
    for (int st = 0; st < 2; st++) {
        float mx = acc[0][st][0];
        #pragma unroll
        for (int ct = 0; ct < CT; ct++)
            #pragma unroll
            for (int r = 0; r < 4; r++) mx = fmaxf(mx, acc[ct][st][r]);
        mx = fmaxf(mx, __shfl_xor(mx, 16));
        mx = fmaxf(mx, __shfl_xor(mx, 32));
        if (lg == 0) {
            const int si = wv * 32 + st * 16 + lr;   // token within block
            const int s  = s0 + si;
            const float mk = mask[b * Ss + s];
            l_sh[si] = mx * mk + (mk - 1.0f) * NEGV;
        }
    }
    __syncthreads();

    // block max M_b over the 128 logits
    if (t < 128) {
        float v = l_sh[t];
        #pragma unroll
        for (int o = 32; o >= 1; o >>= 1) v = fmaxf(v, __shfl_xor(v, o));
        if ((t & 63) == 0) red2[t >> 6] = v;
    }
    __syncthreads();
    const float Mb = fmaxf(red2[0], red2[1]);
    if (t < 128) w_sh[t] = expf(l_sh[t] - Mb);
    __syncthreads();
    if (t < 128) {
        float z = w_sh[t];
        #pragma unroll
        for (int o = 32; o >= 1; o >>= 1) z += __shfl_xor(z, o);
        if ((t & 63) == 0) zred[t >> 6] = z;
    }
    __syncthreads();

    // block-local ctx partial: P[d] = sum_s w_sh[s] * e[s0+s][d]  (L2-hot)
    {
        const float* eb = embeds + ((size_t)b * Ss + s0) * Dd + t * 4;
        f32x4 ca = (f32x4){0.f, 0.f, 0.f, 0.f};
        #pragma unroll 8
        for (int s = 0; s < 128; s++) {
            const float wgt = w_sh[s];
            const f32x4 ev = *(const f32x4*)(eb + (size_t)s * Dd);
            ca[0] = fmaf(wgt, ev[0], ca[0]);
            ca[1] = fmaf(wgt, ev[1], ca[1]);
            ca[2] = fmaf(wgt, ev[2], ca[2]);
            ca[3] = fmaf(wgt, ev[3], ca[3]);
        }
        *(f32x4*)(partial + ((size_t)(b * NBLK + blk)) * Dd + t * 4) = ca;
        if (t == 0) {
            mblk[b * NBLK + blk] = Mb;
            zblk[b * NBLK + blk] = zred[0] + zred[1];
        }
    }
}

// ------- Pass 2: global flash combine + tok_diag -------
__global__ __launch_bounds__(256) void k_finish(
    const float* __restrict__ mblk, const float* __restrict__ zblk,
    const float* __restrict__ partial, const float* __restrict__ tok_diag,
    float* __restrict__ out)
{
    __shared__ float cf[NBLK];
    const int b = blockIdx.x, t = threadIdx.x;

    if (t < 64) {
        const float mv = (t < NBLK) ? mblk[b * NBLK + t] : -3.4e38f;
        float M = mv;
        #pragma unroll
        for (int o = 32; o >= 1; o >>= 1) M = fmaxf(M, __shfl_xor(M, o));
        const float zv = (t < NBLK) ? zblk[b * NBLK + t] * expf(mv - M) : 0.f;
        float Z = zv;
        #pragma unroll
        for (int o = 32; o >= 1; o >>= 1) Z += __shfl_xor(Z, o);
        if (t < NBLK) cf[t] = expf(mv - M) / Z;
    }
    __syncthreads();

    const int d = t * 4;
    f32x4 a = (f32x4){0.f, 0.f, 0.f, 0.f};
    #pragma unroll
    for (int j = 0; j < NBLK; j++) {
        const float c = cf[j];
        const f32x4 p = *(const f32x4*)(partial + ((size_t)(b * NBLK + j)) * Dd + d);
        a[0] = fmaf(c, p[0], a[0]);
        a[1] = fmaf(c, p[1], a[1]);
        a[2] = fmaf(c, p[2], a[2]);
        a[3] = fmaf(c, p[3], a[3]);
    }
    const f32x4 td = *(const f32x4*)(tok_diag + d);
    f32x4 o = a * td;
    *(f32x4*)(out + (size_t)b * Dd + d) = o;
}

extern "C" void kernel_launch(void* const* d_in, const int* in_sizes, int n_in,
                              void* d_out, int out_size, void* d_ws, size_t ws_size,
                              hipStream_t stream) {
    const float* embeds    = (const float*)d_in[0];
    const float* mask      = (const float*)d_in[1];
    const float* latent    = (const float*)d_in[2];
    const float* att_diag  = (const float*)d_in[3];
    const float* tok_diag  = (const float*)d_in[4];
    const float* pos_table = (const float*)d_in[5];
    const float* tok_mult  = (const float*)d_in[6];
    const int*   rel_ids   = (const int*)d_in[7];
    float* out = (float*)d_out;

    char* ws = (char*)d_ws;
    _Float16* whi    = (_Float16*)(ws);              // 512 KB
    float*    partial= (float*)(ws + 524288);        // 2 MB
    float*    mblk   = (float*)(ws + 2621440);       // 2 KB
    float*    zblk   = (float*)(ws + 2623488);       // 2 KB

    k_prep_w<<<(Cc * Dd) / 256, 256, 0, stream>>>(latent, att_diag, whi);
    k_scores_mfma<<<Bb * NBLK, 256, 0, stream>>>(
        embeds, mask, pos_table, tok_mult, rel_ids, whi, partial, mblk, zblk);
    k_finish<<<Bb, 256, 0, stream>>>(mblk, zblk, partial, tok_diag, out);
}